// Round 7
// baseline (168.475 us; speedup 1.0000x reference)
//
#include <hip/hip_runtime.h>
#include <hip/hip_bf16.h>

#define BATCH 65536
#define IN    64
#define H     128
#define NA    16
#define RPB   32     // rows per block (R7: halved to double blocks/CU)
#define HPAD  136    // pad bf16 elems; 272 B row stride, 16B-aligned

typedef __bf16 bf16x8 __attribute__((ext_vector_type(8)));
typedef float  f32x4  __attribute__((ext_vector_type(4)));

union Frag { uint4 u; bf16x8 v; };

#define EXP2F(v) __builtin_amdgcn_exp2f(v)
#define RCPF(v)  __builtin_amdgcn_rcpf(v)
#define K1 1.442695041f   // log2(e)
#define K2 2.885390082f   // 2*log2(e)

// ALL tensors are float32 (R5/R6: WRITE_SIZE == 65536*17*4B exactly; R2/R3
// passed only via the all-f32 path). Load f32, convert to bf16 fragments.
__device__ __forceinline__ Frag g8f(const float* p) {
    const float4 a = *reinterpret_cast<const float4*>(p);
    const float4 b = *reinterpret_cast<const float4*>(p + 4);
    Frag f;
    f.v[0] = (__bf16)a.x; f.v[1] = (__bf16)a.y; f.v[2] = (__bf16)a.z; f.v[3] = (__bf16)a.w;
    f.v[4] = (__bf16)b.x; f.v[5] = (__bf16)b.y; f.v[6] = (__bf16)b.z; f.v[7] = (__bf16)b.w;
    return f;
}

__device__ __forceinline__ float clamp30(float v) {
    return __builtin_fminf(__builtin_fmaxf(v, -30.0f), 30.0f);
}

// h = sigmoid(o) * tanh(sigmoid(i) * tanh(g)); f-gate dead (c_prev = 0).
// 4 exp + 2 rcp; +-30 clamp makes exp2 args <= 87 < 128 (no inf) and is
// exact since sigma/tanh saturate in bf16 far below +-30.
__device__ __forceinline__ float lstm_h(float ip, float gp, float op) {
    ip = clamp30(ip); gp = clamp30(gp); op = clamp30(op);
    const float Ei = EXP2F(-K1 * ip);
    const float Eg = EXP2F( K2 * gp);
    const float c2 = (Eg - 1.0f) * RCPF((1.0f + Ei) * (Eg + 1.0f));
    const float Eo = EXP2F(-K1 * op);
    const float Ec = EXP2F( K2 * c2);
    return (Ec - 1.0f) * RCPF((1.0f + Eo) * (Ec + 1.0f));
}

// Block = 256 threads = 4 waves, owns 32 batch rows (2 M-subtiles).
// Wave w computes c-tiles {2w, 2w+1} x 3 gates; h0/h1 shared via LDS.
// __launch_bounds__(256, 8): force VGPR <= 64 so 8 blocks/CU (32 waves) fit;
// LDS 17.4 KB/block allows 9. Live state ~60 VGPR by construction.
__global__ __launch_bounds__(256, 8)
void lstm_fused(const float* __restrict__ x,
                const float* __restrict__ Wih0,
                const float* __restrict__ bih0,
                const float* __restrict__ bhh0,
                const float* __restrict__ Wih1,
                const float* __restrict__ bih1,
                const float* __restrict__ bhh1,
                const float* __restrict__ Wp,
                const float* __restrict__ bp,
                const float* __restrict__ Wv,
                const float* __restrict__ bv,
                float* __restrict__ out)
{
    __shared__ __align__(16) __hip_bfloat16 hb0[RPB * HPAD];
    __shared__ __align__(16) __hip_bfloat16 hb1[RPB * HPAD];

    const int wave   = threadIdx.x >> 6;
    const int lane   = threadIdx.x & 63;
    const int m16    = lane & 15;
    const int quad   = lane >> 4;
    const int c0     = wave * 2;
    const int rowblk = blockIdx.x * RPB;
    const f32x4 vzero = {0.f, 0.f, 0.f, 0.f};
    const int kGoff[3] = {0, 2 * H, 3 * H};   // gate rows: i, g, o

    // ===== GEMM1: gates0 = x @ Wih0[igo]^T ; h0 -> LDS =====
    Frag a1[2][2];
#pragma unroll
    for (int s = 0; s < 2; ++s)
#pragma unroll
        for (int kt = 0; kt < 2; ++kt)
            a1[s][kt] = g8f(x + (size_t)(rowblk + s * 16 + m16) * IN + kt * 32 + quad * 8);

#pragma unroll
    for (int ci = 0; ci < 2; ++ci) {
        const int c = c0 + ci;
        f32x4 acc[3][2];
#pragma unroll
        for (int G = 0; G < 3; ++G)
#pragma unroll
            for (int s = 0; s < 2; ++s) acc[G][s] = vzero;

#pragma unroll
        for (int kt = 0; kt < 2; ++kt) {
            Frag b[3];
#pragma unroll
            for (int G = 0; G < 3; ++G)
                b[G] = g8f(Wih0 + (size_t)(kGoff[G] + c * 16 + m16) * IN + kt * 32 + quad * 8);
#pragma unroll
            for (int G = 0; G < 3; ++G)
#pragma unroll
                for (int s = 0; s < 2; ++s)
                    acc[G][s] = __builtin_amdgcn_mfma_f32_16x16x32_bf16(a1[s][kt].v, b[G].v, acc[G][s], 0, 0, 0);
        }

        float bi[3];
#pragma unroll
        for (int G = 0; G < 3; ++G) {
            const int n = kGoff[G] + c * 16 + m16;
            bi[G] = bih0[n] + bhh0[n];
        }
#pragma unroll
        for (int s = 0; s < 2; ++s)
#pragma unroll
            for (int r = 0; r < 4; ++r) {
                const float h = lstm_h(acc[0][s][r] + bi[0],
                                       acc[1][s][r] + bi[1],
                                       acc[2][s][r] + bi[2]);
                hb0[(s * 16 + quad * 4 + r) * HPAD + c * 16 + m16] = __float2bfloat16(h);
            }
    }
    __syncthreads();

    // ===== GEMM2: gates1 = h0 @ Wih1[igo]^T ; h1 -> LDS =====
#pragma unroll
    for (int ci = 0; ci < 2; ++ci) {
        const int c = c0 + ci;
        f32x4 acc[3][2];
#pragma unroll
        for (int G = 0; G < 3; ++G)
#pragma unroll
            for (int s = 0; s < 2; ++s) acc[G][s] = vzero;

#pragma unroll
        for (int kt = 0; kt < 4; ++kt) {
            Frag a[2];
#pragma unroll
            for (int s = 0; s < 2; ++s)
                a[s].u = *reinterpret_cast<const uint4*>(hb0 + (s * 16 + m16) * HPAD + kt * 32 + quad * 8);
            Frag b[3];
#pragma unroll
            for (int G = 0; G < 3; ++G)
                b[G] = g8f(Wih1 + (size_t)(kGoff[G] + c * 16 + m16) * H + kt * 32 + quad * 8);
#pragma unroll
            for (int G = 0; G < 3; ++G)
#pragma unroll
                for (int s = 0; s < 2; ++s)
                    acc[G][s] = __builtin_amdgcn_mfma_f32_16x16x32_bf16(a[s].v, b[G].v, acc[G][s], 0, 0, 0);
        }

        float bi[3];
#pragma unroll
        for (int G = 0; G < 3; ++G) {
            const int n = kGoff[G] + c * 16 + m16;
            bi[G] = bih1[n] + bhh1[n];
        }
#pragma unroll
        for (int s = 0; s < 2; ++s)
#pragma unroll
            for (int r = 0; r < 4; ++r) {
                const float h = lstm_h(acc[0][s][r] + bi[0],
                                       acc[1][s][r] + bi[1],
                                       acc[2][s][r] + bi[2]);
                hb1[(s * 16 + quad * 4 + r) * HPAD + c * 16 + m16] = __float2bfloat16(h);
            }
    }
    __syncthreads();

    // ===== Heads: waves 0,1 -> policy s-tile w; waves 2,3 -> value s-tile w-2
    const int shead = wave & 1;
    Frag a3[4];
#pragma unroll
    for (int kt = 0; kt < 4; ++kt)
        a3[kt].u = *reinterpret_cast<const uint4*>(hb1 + (shead * 16 + m16) * HPAD + kt * 32 + quad * 8);

    if (wave < 2) {
        Frag bpf[4];
#pragma unroll
        for (int kt = 0; kt < 4; ++kt)
            bpf[kt] = g8f(Wp + (size_t)m16 * H + kt * 32 + quad * 8);
        const float pbias = bp[m16];

        f32x4 pa = vzero;
#pragma unroll
        for (int kt = 0; kt < 4; ++kt)
            pa = __builtin_amdgcn_mfma_f32_16x16x32_bf16(a3[kt].v, bpf[kt].v, pa, 0, 0, 0);
#pragma unroll
        for (int r = 0; r < 4; ++r) {
            const int row = rowblk + shead * 16 + quad * 4 + r;
            out[(size_t)row * NA + m16] = pa[r] + pbias;
        }
    } else {
        Frag bvf[4];
#pragma unroll
        for (int kt = 0; kt < 4; ++kt) {
            if (m16 == 0) bvf[kt] = g8f(Wv + kt * 32 + quad * 8);
            else          bvf[kt].u = make_uint4(0u, 0u, 0u, 0u);
        }
        const float vbias = bv[0];

        f32x4 va = vzero;
#pragma unroll
        for (int kt = 0; kt < 4; ++kt)
            va = __builtin_amdgcn_mfma_f32_16x16x32_bf16(a3[kt].v, bvf[kt].v, va, 0, 0, 0);
        if (m16 == 0) {
#pragma unroll
            for (int r = 0; r < 4; ++r) {
                const int row = rowblk + shead * 16 + quad * 4 + r;
                out[(size_t)BATCH * NA + row] = va[r] + vbias;
            }
        }
    }
}

extern "C" void kernel_launch(void* const* d_in, const int* in_sizes, int n_in,
                              void* d_out, int out_size, void* d_ws, size_t ws_size,
                              hipStream_t stream) {
    // setup_inputs order: x, Wih0, Whh0, bih0, bhh0, Wih1, Whh1, bih1, bhh1, Wp, bp, Wv, bv
    // Whh0 (idx 2) / Whh1 (idx 6) dead (h_prev = 0); f-gate dead (c_prev = 0).
    // ALL tensors float32 (proven R5/R6 via WRITE_SIZE + passing f32 path).
    lstm_fused<<<dim3(BATCH / RPB), dim3(256), 0, stream>>>(
        (const float*)d_in[0], (const float*)d_in[1],
        (const float*)d_in[3], (const float*)d_in[4],
        (const float*)d_in[5], (const float*)d_in[7],
        (const float*)d_in[8], (const float*)d_in[9],
        (const float*)d_in[10], (const float*)d_in[11],
        (const float*)d_in[12], (float*)d_out);
}

// Round 8
// 121.347 us; speedup vs baseline: 1.3884x; 1.3884x over previous
//
#include <hip/hip_runtime.h>
#include <hip/hip_bf16.h>

#define BATCH 65536
#define IN    64
#define H     128
#define NA    16
#define RPB   32                         // rows per block-iteration
#define NBLK  512                        // persistent blocks = 2 per CU
#define NITER (BATCH / (NBLK * RPB))     // 4
#define HPAD  136                        // h-tile row stride (bf16): 2-way-free
#define W0PAD 72                         // Wih0 LDS row stride (bf16): 2-way-free

typedef __bf16 bf16x8 __attribute__((ext_vector_type(8)));
typedef float  f32x4  __attribute__((ext_vector_type(4)));

union Frag { uint4 u; bf16x8 v; };
struct F32x8 { float4 a, b; };

#define EXP2F(v) __builtin_amdgcn_exp2f(v)
#define RCPF(v)  __builtin_amdgcn_rcpf(v)
#define K1 1.442695041f   // log2(e)
#define K2 2.885390082f   // 2*log2(e)

// ALL tensors float32 (R5/R6: WRITE_SIZE == 65536*17*4B; f32 path passes).
__device__ __forceinline__ F32x8 ld8f(const float* p) {
    F32x8 r;
    r.a = *reinterpret_cast<const float4*>(p);
    r.b = *reinterpret_cast<const float4*>(p + 4);
    return r;
}
__device__ __forceinline__ Frag cvt8(F32x8 x) {
    Frag f;
    f.v[0]=(__bf16)x.a.x; f.v[1]=(__bf16)x.a.y; f.v[2]=(__bf16)x.a.z; f.v[3]=(__bf16)x.a.w;
    f.v[4]=(__bf16)x.b.x; f.v[5]=(__bf16)x.b.y; f.v[6]=(__bf16)x.b.z; f.v[7]=(__bf16)x.b.w;
    return f;
}
__device__ __forceinline__ Frag g8f(const float* p) { return cvt8(ld8f(p)); }

__device__ __forceinline__ float clamp30(float v) {
    return __builtin_fminf(__builtin_fmaxf(v, -30.0f), 30.0f);
}
// h = sigmoid(o)*tanh(sigmoid(i)*tanh(g)); f-gate dead (c_prev=0). 4 exp+2 rcp,
// +-30 clamp keeps exp2 args < 128 (no inf) and is exact (sigma/tanh saturated).
__device__ __forceinline__ float lstm_h(float ip, float gp, float op) {
    ip = clamp30(ip); gp = clamp30(gp); op = clamp30(op);
    const float Ei = EXP2F(-K1 * ip);
    const float Eg = EXP2F( K2 * gp);
    const float c2 = (Eg - 1.0f) * RCPF((1.0f + Ei) * (Eg + 1.0f));
    const float Eo = EXP2F(-K1 * op);
    const float Ec = EXP2F( K2 * c2);
    return (Ec - 1.0f) * RCPF((1.0f + Eo) * (Ec + 1.0f));
}

// Persistent block = 256 threads = 4 waves. Wave w owns c-tiles {2w,2w+1} x 3
// gates. Weights loaded ONCE: Wih0 slice -> LDS, Wih1 slice + heads -> regs.
// Inner loop: x (HBM, prefetched) -> GEMM1 -> LDS -> GEMM2 -> LDS -> heads.
// R7 post-mortem: kernel was L2-latency/MLP-bound on per-iteration weight
// re-fetch; making weights resident removes that path entirely.
__global__ __launch_bounds__(256, 2)
void lstm_fused(const float* __restrict__ x,
                const float* __restrict__ Wih0,
                const float* __restrict__ bih0,
                const float* __restrict__ bhh0,
                const float* __restrict__ Wih1,
                const float* __restrict__ bih1,
                const float* __restrict__ bhh1,
                const float* __restrict__ Wp,
                const float* __restrict__ bp,
                const float* __restrict__ Wv,
                const float* __restrict__ bv,
                float* __restrict__ out)
{
    __shared__ __align__(16) __hip_bfloat16 w0s[4 * 6 * 16 * W0PAD]; // 55.3 KB
    __shared__ __align__(16) __hip_bfloat16 hb0[RPB * HPAD];         //  8.7 KB
    __shared__ __align__(16) __hip_bfloat16 hb1[RPB * HPAD];         //  8.7 KB

    const int wave = threadIdx.x >> 6;
    const int lane = threadIdx.x & 63;
    const int m16  = lane & 15;
    const int quad = lane >> 4;
    const f32x4 vzero = {0.f, 0.f, 0.f, 0.f};
    const int kGoff[3] = {0, 2 * H, 3 * H};   // gate rows: i, g, o

    __hip_bfloat16* myw0 = w0s + wave * (6 * 16 * W0PAD);

    // ---- Prologue (once): Wih0 slice -> LDS as bf16, padded rows ----
#pragma unroll
    for (int ch = 0; ch < 6; ++ch) {          // ch = G*2 + ci
        const int G = ch >> 1, ci = ch & 1;
        const int grow = kGoff[G] + (wave * 2 + ci) * 16 + m16;
        const float* src = Wih0 + (size_t)grow * IN + quad * 16;
        Frag flo = g8f(src), fhi = g8f(src + 8);
        __hip_bfloat16* dst = myw0 + (ch * 16 + m16) * W0PAD + quad * 16;
        *reinterpret_cast<uint4*>(dst)     = flo.u;
        *reinterpret_cast<uint4*>(dst + 8) = fhi.u;
    }

    // ---- Wih1 slice -> registers (24 B-frags = 96 VGPR) ----
    Frag b1[3][2][4];
#pragma unroll
    for (int G = 0; G < 3; ++G)
#pragma unroll
        for (int ci = 0; ci < 2; ++ci)
#pragma unroll
            for (int kt = 0; kt < 4; ++kt)
                b1[G][ci][kt] = g8f(Wih1 + (size_t)(kGoff[G] + (wave * 2 + ci) * 16 + m16) * H
                                    + kt * 32 + quad * 8);

    // ---- Head weights -> registers (waves 0,1: policy; 2,3: value) ----
    const int shead = wave & 1;
    Frag bh[4];
    float hbias;
    if (wave < 2) {
#pragma unroll
        for (int kt = 0; kt < 4; ++kt)
            bh[kt] = g8f(Wp + (size_t)m16 * H + kt * 32 + quad * 8);
        hbias = bp[m16];
    } else {
#pragma unroll
        for (int kt = 0; kt < 4; ++kt) {
            if (m16 == 0) bh[kt] = g8f(Wv + kt * 32 + quad * 8);
            else          bh[kt].u = make_uint4(0u, 0u, 0u, 0u);
        }
        hbias = bv[0];
    }

    // ---- Biases (once) ----
    float bi0[3][2], bi1[3][2];
#pragma unroll
    for (int G = 0; G < 3; ++G)
#pragma unroll
        for (int ci = 0; ci < 2; ++ci) {
            const int n = kGoff[G] + (wave * 2 + ci) * 16 + m16;
            bi0[G][ci] = bih0[n] + bhh0[n];
            bi1[G][ci] = bih1[n] + bhh1[n];
        }

    __syncthreads();

    // ---- x prefetch for iteration 0 (raw f32; cvt at use) ----
    F32x8 xraw[2][2];
    {
        const int r0 = blockIdx.x * RPB;
#pragma unroll
        for (int s = 0; s < 2; ++s)
#pragma unroll
            for (int kt = 0; kt < 2; ++kt)
                xraw[s][kt] = ld8f(x + (size_t)(r0 + s * 16 + m16) * IN + kt * 32 + quad * 8);
    }

    for (int it = 0; it < NITER; ++it) {
        const int rowblk = (blockIdx.x + it * NBLK) * RPB;

        Frag a1[2][2];
#pragma unroll
        for (int s = 0; s < 2; ++s)
#pragma unroll
            for (int kt = 0; kt < 2; ++kt)
                a1[s][kt] = cvt8(xraw[s][kt]);

        // prefetch next tile's x — overlaps all compute below (~2k cycles)
        if (it + 1 < NITER) {
            const int r0 = (blockIdx.x + (it + 1) * NBLK) * RPB;
#pragma unroll
            for (int s = 0; s < 2; ++s)
#pragma unroll
                for (int kt = 0; kt < 2; ++kt)
                    xraw[s][kt] = ld8f(x + (size_t)(r0 + s * 16 + m16) * IN + kt * 32 + quad * 8);
        }

        // ===== GEMM1: gates0 = x @ Wih0[igo]^T (B from LDS) ; h0 -> LDS =====
#pragma unroll
        for (int ci = 0; ci < 2; ++ci) {
            f32x4 acc[3][2];
#pragma unroll
            for (int G = 0; G < 3; ++G)
#pragma unroll
                for (int s = 0; s < 2; ++s) acc[G][s] = vzero;

#pragma unroll
            for (int kt = 0; kt < 2; ++kt) {
                Frag b[3];
#pragma unroll
                for (int G = 0; G < 3; ++G)
                    b[G].u = *reinterpret_cast<const uint4*>(
                        myw0 + ((G * 2 + ci) * 16 + m16) * W0PAD + kt * 32 + quad * 8);
#pragma unroll
                for (int G = 0; G < 3; ++G)
#pragma unroll
                    for (int s = 0; s < 2; ++s)
                        acc[G][s] = __builtin_amdgcn_mfma_f32_16x16x32_bf16(
                            a1[s][kt].v, b[G].v, acc[G][s], 0, 0, 0);
            }
#pragma unroll
            for (int s = 0; s < 2; ++s)
#pragma unroll
                for (int r = 0; r < 4; ++r) {
                    const float h = lstm_h(acc[0][s][r] + bi0[0][ci],
                                           acc[1][s][r] + bi0[1][ci],
                                           acc[2][s][r] + bi0[2][ci]);
                    hb0[(s * 16 + quad * 4 + r) * HPAD + (wave * 2 + ci) * 16 + m16] =
                        __float2bfloat16(h);
                }
        }
        __syncthreads();

        // ===== GEMM2: gates1 = h0 @ Wih1[igo]^T (B from regs) ; h1 -> LDS ===
#pragma unroll
        for (int ci = 0; ci < 2; ++ci) {
            f32x4 acc[3][2];
#pragma unroll
            for (int G = 0; G < 3; ++G)
#pragma unroll
                for (int s = 0; s < 2; ++s) acc[G][s] = vzero;

#pragma unroll
            for (int kt = 0; kt < 4; ++kt) {
                Frag a[2];
#pragma unroll
                for (int s = 0; s < 2; ++s)
                    a[s].u = *reinterpret_cast<const uint4*>(
                        hb0 + (s * 16 + m16) * HPAD + kt * 32 + quad * 8);
#pragma unroll
                for (int G = 0; G < 3; ++G)
#pragma unroll
                    for (int s = 0; s < 2; ++s)
                        acc[G][s] = __builtin_amdgcn_mfma_f32_16x16x32_bf16(
                            a[s].v, b1[G][ci][kt].v, acc[G][s], 0, 0, 0);
            }
#pragma unroll
            for (int s = 0; s < 2; ++s)
#pragma unroll
                for (int r = 0; r < 4; ++r) {
                    const float h = lstm_h(acc[0][s][r] + bi1[0][ci],
                                           acc[1][s][r] + bi1[1][ci],
                                           acc[2][s][r] + bi1[2][ci]);
                    hb1[(s * 16 + quad * 4 + r) * HPAD + (wave * 2 + ci) * 16 + m16] =
                        __float2bfloat16(h);
                }
        }
        __syncthreads();
        // hazards: hb0 rewritten only after next iter's barrier#2-...-barrier#1
        // chain; hb1 read by heads below, rewritten only after next barrier#1.

        // ===== Heads (B from regs): waves 0,1 policy s=w; 2,3 value s=w-2 ====
        Frag a3[4];
#pragma unroll
        for (int kt = 0; kt < 4; ++kt)
            a3[kt].u = *reinterpret_cast<const uint4*>(
                hb1 + (shead * 16 + m16) * HPAD + kt * 32 + quad * 8);

        f32x4 ha = vzero;
#pragma unroll
        for (int kt = 0; kt < 4; ++kt)
            ha = __builtin_amdgcn_mfma_f32_16x16x32_bf16(a3[kt].v, bh[kt].v, ha, 0, 0, 0);

        if (wave < 2) {
#pragma unroll
            for (int r = 0; r < 4; ++r) {
                const int row = rowblk + shead * 16 + quad * 4 + r;
                out[(size_t)row * NA + m16] = ha[r] + hbias;
            }
        } else if (m16 == 0) {
#pragma unroll
            for (int r = 0; r < 4; ++r) {
                const int row = rowblk + shead * 16 + quad * 4 + r;
                out[(size_t)BATCH * NA + row] = ha[r] + hbias;
            }
        }
    }
}

extern "C" void kernel_launch(void* const* d_in, const int* in_sizes, int n_in,
                              void* d_out, int out_size, void* d_ws, size_t ws_size,
                              hipStream_t stream) {
    // setup_inputs order: x, Wih0, Whh0, bih0, bhh0, Wih1, Whh1, bih1, bhh1, Wp, bp, Wv, bv
    // Whh0 (idx 2) / Whh1 (idx 6) dead (h_prev = 0); f-gate dead (c_prev = 0).
    // ALL tensors float32 (proven R5/R6 via WRITE_SIZE + passing f32 path).
    lstm_fused<<<dim3(NBLK), dim3(256), 0, stream>>>(
        (const float*)d_in[0], (const float*)d_in[1],
        (const float*)d_in[3], (const float*)d_in[4],
        (const float*)d_in[5], (const float*)d_in[7],
        (const float*)d_in[8], (const float*)d_in[9],
        (const float*)d_in[10], (const float*)d_in[11],
        (const float*)d_in[12], (float*)d_out);
}